// Round 1
// baseline (2847.179 us; speedup 1.0000x reference)
//
#include <hip/hip_runtime.h>
#include <hip/hip_bf16.h>

// CloudCrop fused kernel: one block per (b,s) group.
// B=2, S=1024, N=10000, C=128, NSAMPLE=64, hidden=256.

constexpr int Nn = 10000;
constexpr int Cc = 128;
constexpr float RAD2 = 0.05f * 0.05f;
constexpr float HMINf = -0.02f, HMAXf = 0.02f;
constexpr float INVV = 0.99999500003749968747f; // 1/sqrt(1+1e-5)

#define ATT_STRIDE 68  // padded stride for q/att (16B aligned, spreads banks)

__launch_bounds__(256, 1)
__global__ void cloudcrop_kernel(
    const float* __restrict__ seed,   // (B,S,3)
    const float* __restrict__ pc,     // (B,N,3)
    const float* __restrict__ rot,    // (B,S,3,3)
    const float* __restrict__ up,     // (B,C,N)
    const float* __restrict__ mlp_w,  // (256,131)
    const float* __restrict__ mlp_b,  // (256)
    const float* __restrict__ bn1g,
    const float* __restrict__ bn1b,
    const float* __restrict__ qk_w,   // (64,256)
    const float* __restrict__ v_w,    // (256,256)
    const float* __restrict__ v_b,
    const float* __restrict__ t_w,    // (256,256)
    const float* __restrict__ t_b,
    const float* __restrict__ bn2g,
    const float* __restrict__ bn2b,
    float* __restrict__ out)          // (B,256,S)
{
    // LDS: xs 64KB | reg1 (gT[131][64] f32, later qT[64][68]+att[64][68]) | misc
    __shared__ float xs[64 * 256];          // x (later y = x - x_r)
    __shared__ float reg1[2 * 64 * ATT_STRIDE]; // 34816B >= gT (33536B)
    __shared__ int   idx_s[64];
    __shared__ float colpart[4 * 64];
    __shared__ float colsum[64];

    const int grp = blockIdx.x;
    const int b = grp >> 10;
    const int s = grp & 1023;
    const int t = threadIdx.x;
    const int lane = t & 63;
    const int w = t >> 6;

    float* gT  = reg1;                     // [131][64], c-major (xyz rows 0..2)
    float* qT  = reg1;                     // [64][ATT_STRIDE]
    float* att = reg1 + 64 * ATT_STRIDE;   // [64][ATT_STRIDE]

    // ---------------- Phase 0: neighbor selection (wave 0 only) -------------
    if (w == 0) {
        const float sx = seed[grp * 3 + 0];
        const float sy = seed[grp * 3 + 1];
        const float sz = seed[grp * 3 + 2];
        const float R0 = rot[grp * 9 + 0], R1 = rot[grp * 9 + 1], R2 = rot[grp * 9 + 2];
        const float R3 = rot[grp * 9 + 3], R4 = rot[grp * 9 + 4], R5 = rot[grp * 9 + 5];
        const float R6 = rot[grp * 9 + 6], R7 = rot[grp * 9 + 7], R8 = rot[grp * 9 + 8];

        int count = 0;
        int fidx = 0; float frx = 0.f, fry = 0.f, frz = 0.f;
        bool havef = false;

        for (int base = 0; base < Nn && count < 64; base += 64) {
            const int n = base + lane;
            bool m = false; float rx = 0.f, ry = 0.f, rz = 0.f;
            if (n < Nn) {
                const float px = pc[(b * Nn + n) * 3 + 0] - sx;
                const float py = pc[(b * Nn + n) * 3 + 1] - sy;
                const float pz = pc[(b * Nn + n) * 3 + 2] - sz;
                rx = px * R0 + py * R3 + pz * R6;
                ry = px * R1 + py * R4 + pz * R7;
                rz = px * R2 + py * R5 + pz * R8;
                m = (ry * ry + rz * rz < RAD2) && (rx > HMINf) && (rx < HMAXf);
            }
            const unsigned long long bal = __ballot(m);
            const int below = __popcll(bal & ((1ull << lane) - 1ull));
            const int pos = count + below;
            if (m && pos < 64) {
                idx_s[pos] = n;
                gT[0 * 64 + pos] = rx; gT[1 * 64 + pos] = ry; gT[2 * 64 + pos] = rz;
                if (pos == 0) { fidx = n; frx = rx; fry = ry; frz = rz; havef = true; }
            }
            count += __popcll(bal);
        }
        const int total = count < 64 ? count : 64;
        const unsigned long long fb = __ballot(havef);
        if (fb != 0ull) {
            const int src = __ffsll((unsigned long long)fb) - 1;
            fidx = __shfl(fidx, src);
            frx = __shfl(frx, src); fry = __shfl(fry, src); frz = __shfl(frz, src);
        } else {
            fidx = 0;
            const float px = pc[(b * Nn) * 3 + 0] - sx;
            const float py = pc[(b * Nn) * 3 + 1] - sy;
            const float pz = pc[(b * Nn) * 3 + 2] - sz;
            frx = px * R0 + py * R3 + pz * R6;
            fry = px * R1 + py * R4 + pz * R7;
            frz = px * R2 + py * R5 + pz * R8;
        }
        if (lane >= total) {
            idx_s[lane] = fidx;
            gT[0 * 64 + lane] = frx; gT[1 * 64 + lane] = fry; gT[2 * 64 + lane] = frz;
        }
    }
    __syncthreads();

    // ---------------- Phase 1: feature gather (all threads) -----------------
    {
        const int myn = idx_s[lane];
        #pragma unroll
        for (int it = 0; it < 32; ++it) {
            const int c = w + it * 4; // covers 0..127 across waves
            gT[(3 + c) * 64 + lane] = up[(b * Cc + c) * Nn + myn];
        }
    }
    __syncthreads();

    // ---------------- Phase A: MLP (64x131 @ 131x256) + BN1 + ReLU ----------
    {
        float acc[64];
        const float mb = mlp_b[t];
        #pragma unroll
        for (int k = 0; k < 64; ++k) acc[k] = mb;
        for (int c = 0; c < 131; ++c) {
            const float wc = mlp_w[t * 131 + c];
            const float4* g4 = (const float4*)(gT + c * 64);
            #pragma unroll
            for (int k4 = 0; k4 < 16; ++k4) {
                const float4 g = g4[k4];
                acc[k4 * 4 + 0] += g.x * wc;
                acc[k4 * 4 + 1] += g.y * wc;
                acc[k4 * 4 + 2] += g.z * wc;
                acc[k4 * 4 + 3] += g.w * wc;
            }
        }
        const float g1 = bn1g[t] * INVV, b1 = bn1b[t];
        #pragma unroll
        for (int k = 0; k < 64; ++k) {
            xs[k * 256 + t] = fmaxf(acc[k] * g1 + b1, 0.0f);
        }
    }
    __syncthreads();

    // ---------------- Phase B: q = x @ qk_w^T  (64x256 @ 256x64) ------------
    {
        const int qch = lane;
        const int i0 = w * 16;
        float acc[16];
        #pragma unroll
        for (int ii = 0; ii < 16; ++ii) acc[ii] = 0.f;
        const float4* wq4 = (const float4*)(qk_w + qch * 256);
        for (int c4 = 0; c4 < 64; ++c4) {
            const float4 wq = wq4[c4];
            #pragma unroll
            for (int ii = 0; ii < 16; ++ii) {
                const float4 x4 = *(const float4*)(xs + (i0 + ii) * 256 + c4 * 4);
                acc[ii] += x4.x * wq.x + x4.y * wq.y + x4.z * wq.z + x4.w * wq.w;
            }
        }
        #pragma unroll
        for (int ii = 0; ii < 16; ++ii) qT[qch * ATT_STRIDE + i0 + ii] = acc[ii];
    }
    __syncthreads();

    // ---------------- Phase C: scores, softmax(rows), column sums -----------
    {
        const int i = lane;
        const int j0 = w * 16;
        float qi[64];
        #pragma unroll
        for (int q = 0; q < 64; ++q) qi[q] = qT[q * ATT_STRIDE + i];
        for (int jj = 0; jj < 16; ++jj) {
            const int j = j0 + jj;
            float sacc = 0.f;
            #pragma unroll
            for (int q = 0; q < 64; ++q) sacc += qi[q] * qT[q * ATT_STRIDE + j];
            att[i * ATT_STRIDE + j] = sacc;
        }
    }
    __syncthreads();
    {
        for (int r = 0; r < 16; ++r) {
            const int i = w * 16 + r;
            const float v = att[i * ATT_STRIDE + lane];
            float mx = v;
            #pragma unroll
            for (int d = 1; d < 64; d <<= 1) mx = fmaxf(mx, __shfl_xor(mx, d));
            const float e = __expf(v - mx);
            float sm = e;
            #pragma unroll
            for (int d = 1; d < 64; d <<= 1) sm += __shfl_xor(sm, d);
            att[i * ATT_STRIDE + lane] = e / sm;
        }
    }
    __syncthreads();
    {
        float p = 0.f;
        for (int r = 0; r < 16; ++r) p += att[(w * 16 + r) * ATT_STRIDE + lane];
        colpart[w * 64 + lane] = p;
    }
    __syncthreads();
    if (t < 64) {
        colsum[t] = 1e-9f + colpart[t] + colpart[64 + t] + colpart[128 + t] + colpart[192 + t];
    }
    __syncthreads();

    // ---------------- Phase D: v = x @ v_w^T + v_b; x_r = att^T-combine -----
    float accr[64];
    {
        float vcol[64];
        const float vb = v_b[t];
        #pragma unroll
        for (int i = 0; i < 64; ++i) vcol[i] = vb;
        const float4* wv4 = (const float4*)(v_w + t * 256);
        for (int k4 = 0; k4 < 64; ++k4) {
            const float4 wv = wv4[k4];
            #pragma unroll
            for (int i = 0; i < 64; ++i) {
                const float4 x4 = *(const float4*)(xs + i * 256 + k4 * 4);
                vcol[i] += x4.x * wv.x + x4.y * wv.y + x4.z * wv.z + x4.w * wv.w;
            }
        }
        #pragma unroll
        for (int j = 0; j < 64; ++j) accr[j] = 0.f;
        #pragma unroll
        for (int i = 0; i < 64; ++i) {
            #pragma unroll
            for (int j4 = 0; j4 < 16; ++j4) {
                const float4 a4 = *(const float4*)(att + i * ATT_STRIDE + j4 * 4);
                accr[j4 * 4 + 0] += a4.x * vcol[i];
                accr[j4 * 4 + 1] += a4.y * vcol[i];
                accr[j4 * 4 + 2] += a4.z * vcol[i];
                accr[j4 * 4 + 3] += a4.w * vcol[i];
            }
        }
        #pragma unroll
        for (int j = 0; j < 64; ++j) accr[j] /= colsum[j]; // colsum includes 1e-9
    }
    __syncthreads(); // all xs reads of Phase D complete before overwrite

    // ---------------- y = x - x_r (overwrite xs); save own x column ---------
    float x_col[64];
    #pragma unroll
    for (int j = 0; j < 64; ++j) {
        const float xv = xs[j * 256 + t];
        x_col[j] = xv;
        xs[j * 256 + t] = xv - accr[j];
    }
    __syncthreads();

    // ---------------- Phase E: t = y @ t_w^T + t_b; BN2+ReLU+res+maxpool ----
    {
        float tacc[64];
        const float tb = t_b[t];
        #pragma unroll
        for (int k = 0; k < 64; ++k) tacc[k] = tb;
        const float4* wt4 = (const float4*)(t_w + t * 256);
        for (int c4 = 0; c4 < 64; ++c4) {
            const float4 wt = wt4[c4];
            #pragma unroll
            for (int k = 0; k < 64; ++k) {
                const float4 y4 = *(const float4*)(xs + k * 256 + c4 * 4);
                tacc[k] += y4.x * wt.x + y4.y * wt.y + y4.z * wt.z + y4.w * wt.w;
            }
        }
        const float g2 = bn2g[t] * INVV, b2 = bn2b[t];
        float m = -3.4e38f;
        #pragma unroll
        for (int k = 0; k < 64; ++k) {
            const float r = fmaxf(tacc[k] * g2 + b2, 0.0f);
            m = fmaxf(m, x_col[k] + r);
        }
        out[(b * 256 + t) * 1024 + s] = m;
    }
}

extern "C" void kernel_launch(void* const* d_in, const int* in_sizes, int n_in,
                              void* d_out, int out_size, void* d_ws, size_t ws_size,
                              hipStream_t stream) {
    (void)in_sizes; (void)n_in; (void)d_ws; (void)ws_size; (void)out_size;
    cloudcrop_kernel<<<2048, 256, 0, stream>>>(
        (const float*)d_in[0],  // seed_xyz
        (const float*)d_in[1],  // pointcloud
        (const float*)d_in[2],  // vp_rot
        (const float*)d_in[3],  // up_feature
        (const float*)d_in[4],  // mlp_w
        (const float*)d_in[5],  // mlp_b
        (const float*)d_in[6],  // bn1_g
        (const float*)d_in[7],  // bn1_b
        (const float*)d_in[8],  // qk_w
        (const float*)d_in[9],  // v_w
        (const float*)d_in[10], // v_b
        (const float*)d_in[11], // t_w
        (const float*)d_in[12], // t_b
        (const float*)d_in[13], // bn2_g
        (const float*)d_in[14], // bn2_b
        (float*)d_out);
}

// Round 2
// 318.004 us; speedup vs baseline: 8.9533x; 8.9533x over previous
//
#include <hip/hip_runtime.h>

// CloudCrop fused MFMA kernel. B=2,S=1024,N=10000,C=128,NS=64,hidden=256.
// prep_weights: f32 weights -> fragment-ordered f16 in ws (368 tiles * 1KB).
// main kernel: one block (4 waves) per (b,s) group; each wave owns 1/4 of
// output columns in every GEMM phase (16x16x32 f16 MFMA).

typedef _Float16 f16;
typedef _Float16 f16x8 __attribute__((ext_vector_type(8)));
typedef _Float16 f16x4v __attribute__((ext_vector_type(4)));
typedef float f32x4 __attribute__((ext_vector_type(4)));

constexpr int Nn = 10000;
constexpr float RAD2 = 0.05f * 0.05f;
constexpr float HMINf = -0.02f, HMAXf = 0.02f;
constexpr float INVV = 0.99999500003749968747f; // 1/sqrt(1+1e-5)

// ws tile map (1KB fragment tiles: [64 lanes][8 f16]):
//   WA: tiles   0..79   (kc 0..4 x ct 0..15)  mlp (K padded 131->160, k: 0..127=feat, 128..130=xyz)
//   WQ: tiles  80..111  (kc 0..7 x ct 0..3)   qk_w
//   WV: tiles 112..239  (kc 0..7 x ct 0..15)  v_w
//   WT: tiles 240..367  (kc 0..7 x ct 0..15)  t_w
#define NTILES 368

__device__ __forceinline__ int swzb(int row, int colbyte) {
    return colbyte ^ ((row & 7) << 4);
}

__global__ void prep_weights(const float* __restrict__ mlp_w,
                             const float* __restrict__ qk_w,
                             const float* __restrict__ v_w,
                             const float* __restrict__ t_w,
                             unsigned char* __restrict__ ws) {
    const int tid = blockIdx.x * 256 + threadIdx.x;
    if (tid >= NTILES * 64) return;
    const int tile = tid >> 6, lane = tid & 63;
    const int ln = lane & 15, kg = lane >> 4;
    f16x8 v;
    if (tile < 80) {
        const int kc = tile / 16, ct = tile % 16;
        const int n = ct * 16 + ln, kb = kc * 32 + kg * 8;
        #pragma unroll
        for (int i = 0; i < 8; ++i) {
            const int k = kb + i;
            float x = (k < 128) ? mlp_w[n * 131 + 3 + k]
                    : ((k < 131) ? mlp_w[n * 131 + (k - 128)] : 0.f);
            v[i] = (f16)x;
        }
    } else if (tile < 112) {
        const int t2 = tile - 80; const int kc = t2 >> 2, ct = t2 & 3;
        const int n = ct * 16 + ln, kb = kc * 32 + kg * 8;
        #pragma unroll
        for (int i = 0; i < 8; ++i) v[i] = (f16)qk_w[n * 256 + kb + i];
    } else if (tile < 240) {
        const int t2 = tile - 112; const int kc = t2 >> 4, ct = t2 & 15;
        const int n = ct * 16 + ln, kb = kc * 32 + kg * 8;
        #pragma unroll
        for (int i = 0; i < 8; ++i) v[i] = (f16)v_w[n * 256 + kb + i];
    } else {
        const int t2 = tile - 240; const int kc = t2 >> 4, ct = t2 & 15;
        const int n = ct * 16 + ln, kb = kc * 32 + kg * 8;
        #pragma unroll
        for (int i = 0; i < 8; ++i) v[i] = (f16)t_w[n * 256 + kb + i];
    }
    *(f16x8*)(ws + (size_t)tid * 16) = v;
}

__launch_bounds__(256, 1)
__global__ void cloudcrop_mfma(
    const float* __restrict__ seed,  // (B,S,3)
    const float* __restrict__ pc,    // (B,N,3)
    const float* __restrict__ rot,   // (B,S,3,3)
    const float* __restrict__ up,    // (B,C,N)
    const float* __restrict__ mlp_b,
    const float* __restrict__ bn1g,
    const float* __restrict__ bn1b,
    const float* __restrict__ v_b,
    const float* __restrict__ t_b,
    const float* __restrict__ bn2g,
    const float* __restrict__ bn2b,
    const unsigned char* __restrict__ ws,
    float* __restrict__ out)         // (B,256,S) f32
{
    // LDS regions (all f16 arrays XOR-swizzled: byte ^= (row&7)<<4)
    __shared__ __align__(16) unsigned char s_xs[64 * 256 * 2];  // X [64][256] stride 512B
    __shared__ __align__(16) unsigned char s_vy[64 * 256 * 2];  // VT [256][64] s128B, then Y [64][256] s512B
    __shared__ __align__(16) unsigned char s_gqs[25600];        // G [64][192] s384B | {attT/Q [64][64] s128B (0..8191), S f32 [64][68] (8192..25599)}
    __shared__ int   cand_i[4][64];
    __shared__ float cand_x[4][64], cand_y[4][64], cand_z[4][64];
    __shared__ int   cand_n[4];
    __shared__ int   idx_s[64];
    __shared__ float colsum[64];

    const int grp = blockIdx.x;
    const int bb = grp >> 10;
    const int s  = grp & 1023;
    const int t  = threadIdx.x;
    const int lane = t & 63;
    const int w    = t >> 6;
    const int ln   = lane & 15;
    const int kg16 = (lane >> 4) * 16;
    const int g4   = (lane >> 4) * 4;

    unsigned char* G = s_gqs;  // [64][192] f16, k: 0..127 feat, 128..130 xyz, 131..159 zero pad

    // ---------- Phase 0: selection scan, wave-parallel over N/4 ranges ------
    {
        const float sx = seed[grp*3+0], sy = seed[grp*3+1], sz = seed[grp*3+2];
        const float R0 = rot[grp*9+0], R1 = rot[grp*9+1], R2 = rot[grp*9+2];
        const float R3 = rot[grp*9+3], R4 = rot[grp*9+4], R5 = rot[grp*9+5];
        const float R6 = rot[grp*9+6], R7 = rot[grp*9+7], R8 = rot[grp*9+8];
        int count = 0;
        const int lo = w * 2500, hi = lo + 2500;
        for (int base = lo; base < hi && count < 64; base += 64) {
            const int n = base + lane;
            bool m = false; float rx = 0.f, ry = 0.f, rz = 0.f;
            if (n < hi) {
                const float px = pc[(bb*Nn + n)*3+0] - sx;
                const float py = pc[(bb*Nn + n)*3+1] - sy;
                const float pz = pc[(bb*Nn + n)*3+2] - sz;
                rx = px*R0 + py*R3 + pz*R6;
                ry = px*R1 + py*R4 + pz*R7;
                rz = px*R2 + py*R5 + pz*R8;
                m = (ry*ry + rz*rz < RAD2) && (rx > HMINf) && (rx < HMAXf);
            }
            const unsigned long long bal = __ballot(m);
            const int below = __popcll(bal & ((1ull << lane) - 1ull));
            const int pos = count + below;
            if (m && pos < 64) {
                cand_i[w][pos] = n;
                cand_x[w][pos] = rx; cand_y[w][pos] = ry; cand_z[w][pos] = rz;
            }
            count += __popcll(bal);
        }
        if (lane == 0) cand_n[w] = count < 64 ? count : 64;
    }
    __syncthreads();

    // ---------- Merge (ordered) + xyz into G + zero pad ---------------------
    if (t < 64) {
        const int c0 = cand_n[0], c1 = cand_n[1], c2 = cand_n[2], c3 = cand_n[3];
        const int o1 = c0, o2 = c0 + c1, o3 = o2 + c2;
        int total = o3 + c3; if (total > 64) total = 64;
        int myi; float rx, ry, rz;
        if (total > 0) {
            const int pp = (t < total) ? t : 0;  // fill slots with global-first
            int sw_, sq;
            if      (pp >= o3) { sw_ = 3; sq = pp - o3; }
            else if (pp >= o2) { sw_ = 2; sq = pp - o2; }
            else if (pp >= o1) { sw_ = 1; sq = pp - o1; }
            else               { sw_ = 0; sq = pp; }
            myi = cand_i[sw_][sq];
            rx = cand_x[sw_][sq]; ry = cand_y[sw_][sq]; rz = cand_z[sw_][sq];
        } else {
            // no candidates at all -> index 0's rel coords
            const float sx = seed[grp*3+0], sy = seed[grp*3+1], sz = seed[grp*3+2];
            const float px = pc[(bb*Nn)*3+0] - sx;
            const float py = pc[(bb*Nn)*3+1] - sy;
            const float pz = pc[(bb*Nn)*3+2] - sz;
            rx = px*rot[grp*9+0] + py*rot[grp*9+3] + pz*rot[grp*9+6];
            ry = px*rot[grp*9+1] + py*rot[grp*9+4] + pz*rot[grp*9+7];
            rz = px*rot[grp*9+2] + py*rot[grp*9+5] + pz*rot[grp*9+8];
            myi = 0;
        }
        idx_s[t] = myi;
        *(f16*)(G + t*384 + swzb(t, 256)) = (f16)rx;  // k=128
        *(f16*)(G + t*384 + swzb(t, 258)) = (f16)ry;  // k=129
        *(f16*)(G + t*384 + swzb(t, 260)) = (f16)rz;  // k=130
    }
    {   // zero pad k = 131..159 (rows t&63, 8 cols per wave)
        const int row = t & 63;
        #pragma unroll
        for (int i = 0; i < 8; ++i) {
            const int c = 131 + w * 8 + i;
            if (c < 160) *(f16*)(G + row*384 + swzb(row, c*2)) = (f16)0.f;
        }
    }
    __syncthreads();

    // ---------- Phase 1: feature gather -> G (k=0..127) ---------------------
    {
        const int myn = idx_s[lane];
        const float* uprow = up + (size_t)bb * 128 * Nn;
        #pragma unroll
        for (int j8 = 0; j8 < 4; ++j8) {
            f16x8 v;
            #pragma unroll
            for (int i = 0; i < 8; ++i) {
                const int c = w * 32 + j8 * 8 + i;
                v[i] = (f16)uprow[(size_t)c * Nn + myn];
            }
            *(f16x8*)(G + lane*384 + swzb(lane, w*64 + j8*16)) = v;
        }
    }
    __syncthreads();

    // ---------- Phase A: H = G(64x160) @ WA -> X f16 (+bias,BN1,ReLU) -------
    {
        f32x4 acc[4][4] = {};
        #pragma unroll 2
        for (int kc = 0; kc < 5; ++kc) {
            f16x8 a[4];
            #pragma unroll
            for (int rt = 0; rt < 4; ++rt) {
                const int row = rt*16 + ln;
                a[rt] = *(const f16x8*)(G + row*384 + swzb(row, kc*64 + kg16));
            }
            #pragma unroll
            for (int j = 0; j < 4; ++j) {
                const f16x8 bf = *(const f16x8*)(ws + (size_t)(kc*16 + 4*w + j)*1024 + lane*16);
                #pragma unroll
                for (int rt = 0; rt < 4; ++rt)
                    acc[rt][j] = __builtin_amdgcn_mfma_f32_16x16x32_f16(a[rt], bf, acc[rt][j], 0, 0, 0);
            }
        }
        #pragma unroll
        for (int j = 0; j < 4; ++j) {
            const int col = (4*w + j)*16 + ln;
            const float mb = mlp_b[col], g1 = bn1g[col]*INVV, b1 = bn1b[col];
            #pragma unroll
            for (int rt = 0; rt < 4; ++rt)
                #pragma unroll
                for (int r = 0; r < 4; ++r) {
                    const int row = rt*16 + g4 + r;
                    const float h = fmaxf((acc[rt][j][r] + mb)*g1 + b1, 0.f);
                    *(f16*)(s_xs + row*512 + swzb(row, col*2)) = (f16)h;
                }
        }
    }
    __syncthreads();

    // ---------- Phase B: Q = X @ WQ (64x64), wave w -> coltile w ------------
    {
        f32x4 accq[4] = {};
        #pragma unroll
        for (int kc = 0; kc < 8; ++kc) {
            const f16x8 bf = *(const f16x8*)(ws + (size_t)(80 + kc*4 + w)*1024 + lane*16);
            #pragma unroll
            for (int rt = 0; rt < 4; ++rt) {
                const int row = rt*16 + ln;
                const f16x8 a = *(const f16x8*)(s_xs + row*512 + swzb(row, kc*64 + kg16));
                accq[rt] = __builtin_amdgcn_mfma_f32_16x16x32_f16(a, bf, accq[rt], 0, 0, 0);
            }
        }
        const int col = w*16 + ln;
        #pragma unroll
        for (int rt = 0; rt < 4; ++rt)
            #pragma unroll
            for (int r = 0; r < 4; ++r) {
                const int row = rt*16 + g4 + r;
                *(f16*)(s_gqs + row*128 + swzb(row, col*2)) = (f16)accq[rt][r];
            }
    }
    __syncthreads();

    // ---------- Phase C: S = Q @ Q^T (64x64) f32 ----------------------------
    {
        f32x4 accs[4] = {};
        #pragma unroll
        for (int kc = 0; kc < 2; ++kc) {
            const int rowb = w*16 + ln;
            const f16x8 bf = *(const f16x8*)(s_gqs + rowb*128 + swzb(rowb, kc*64 + kg16));
            #pragma unroll
            for (int rt = 0; rt < 4; ++rt) {
                const int row = rt*16 + ln;
                const f16x8 a = *(const f16x8*)(s_gqs + row*128 + swzb(row, kc*64 + kg16));
                accs[rt] = __builtin_amdgcn_mfma_f32_16x16x32_f16(a, bf, accs[rt], 0, 0, 0);
            }
        }
        float* Sf = (float*)(s_gqs + 8192);
        const int col = w*16 + ln;
        #pragma unroll
        for (int rt = 0; rt < 4; ++rt)
            #pragma unroll
            for (int r = 0; r < 4; ++r)
                Sf[(rt*16 + g4 + r)*68 + col] = accs[rt][r];
    }
    __syncthreads();

    // ---------- Softmax rows of S -> attT f16 (overwrites Q) ----------------
    {
        float* Sf = (float*)(s_gqs + 8192);
        for (int r = 0; r < 16; ++r) {
            const int i = w*16 + r;
            const float v = Sf[i*68 + lane];
            float mx = v;
            #pragma unroll
            for (int d = 1; d < 64; d <<= 1) mx = fmaxf(mx, __shfl_xor(mx, d));
            const float e = __expf(v - mx);
            float sm = e;
            #pragma unroll
            for (int d = 1; d < 64; d <<= 1) sm += __shfl_xor(sm, d);
            // attT[j=lane][i]
            *(f16*)(s_gqs + lane*128 + swzb(lane, i*2)) = (f16)(e / sm);
        }
    }
    __syncthreads();

    // ---------- colsum[j] = 1e-9 + sum_i att[i][j] (row-sum of attT) --------
    if (t < 64) {
        float ssum = 0.f;
        #pragma unroll
        for (int c8 = 0; c8 < 8; ++c8) {
            const f16x8 vv = *(const f16x8*)(s_gqs + t*128 + swzb(t, c8*16));
            #pragma unroll
            for (int i = 0; i < 8; ++i) ssum += (float)vv[i];
        }
        colsum[t] = 1e-9f + ssum;
    }
    __syncthreads();

    // ---------- Phase D1: V = X @ WV + v_b -> VT f16 [256][64] --------------
    {
        f32x4 accv[4][4] = {};
        #pragma unroll 2
        for (int kc = 0; kc < 8; ++kc) {
            f16x8 a[4];
            #pragma unroll
            for (int rt = 0; rt < 4; ++rt) {
                const int row = rt*16 + ln;
                a[rt] = *(const f16x8*)(s_xs + row*512 + swzb(row, kc*64 + kg16));
            }
            #pragma unroll
            for (int j = 0; j < 4; ++j) {
                const f16x8 bf = *(const f16x8*)(ws + (size_t)(112 + kc*16 + 4*w + j)*1024 + lane*16);
                #pragma unroll
                for (int rt = 0; rt < 4; ++rt)
                    accv[rt][j] = __builtin_amdgcn_mfma_f32_16x16x32_f16(a[rt], bf, accv[rt][j], 0, 0, 0);
            }
        }
        #pragma unroll
        for (int j = 0; j < 4; ++j) {
            const int col = (4*w + j)*16 + ln;  // channel
            const float vb = v_b[col];
            #pragma unroll
            for (int rt = 0; rt < 4; ++rt) {
                f16x4v pk;
                #pragma unroll
                for (int r = 0; r < 4; ++r) pk[r] = (f16)(accv[rt][j][r] + vb);
                const int rbyte = rt*32 + g4*2;  // sample-row bytes
                *(f16x4v*)(s_vy + col*128 + swzb(col, rbyte)) = pk;
            }
        }
    }
    __syncthreads();

    // ---------- Phase D2: XR = attT @ VT^T, /colsum; Y = X - XR -------------
    {
        f32x4 accr[4][4] = {};
        #pragma unroll
        for (int kc = 0; kc < 2; ++kc) {
            f16x8 a[4];
            #pragma unroll
            for (int rt = 0; rt < 4; ++rt) {
                const int row = rt*16 + ln;
                a[rt] = *(const f16x8*)(s_gqs + row*128 + swzb(row, kc*64 + kg16)); // attT
            }
            #pragma unroll
            for (int j = 0; j < 4; ++j) {
                const int vrow = (4*w + j)*16 + ln;  // channel row of VT
                const f16x8 bf = *(const f16x8*)(s_vy + vrow*128 + swzb(vrow, kc*64 + kg16));
                #pragma unroll
                for (int rt = 0; rt < 4; ++rt)
                    accr[rt][j] = __builtin_amdgcn_mfma_f32_16x16x32_f16(a[rt], bf, accr[rt][j], 0, 0, 0);
            }
        }
        __syncthreads();  // all VT reads complete before Y overlays it
        #pragma unroll
        for (int j = 0; j < 4; ++j) {
            const int col = (4*w + j)*16 + ln;
            #pragma unroll
            for (int rt = 0; rt < 4; ++rt)
                #pragma unroll
                for (int r = 0; r < 4; ++r) {
                    const int row = rt*16 + g4 + r;
                    const float xv = (float)(*(const f16*)(s_xs + row*512 + swzb(row, col*2)));
                    const float yv = xv - accr[rt][j][r] / colsum[row];
                    *(f16*)(s_vy + row*512 + swzb(row, col*2)) = (f16)yv;  // Y
                }
        }
    }
    __syncthreads();

    // ---------- Phase E: T = Y @ WT + t_b; out = maxpool(X + relu(BN2)) -----
    {
        f32x4 acct[4][4] = {};
        #pragma unroll 2
        for (int kc = 0; kc < 8; ++kc) {
            f16x8 a[4];
            #pragma unroll
            for (int rt = 0; rt < 4; ++rt) {
                const int row = rt*16 + ln;
                a[rt] = *(const f16x8*)(s_vy + row*512 + swzb(row, kc*64 + kg16));  // Y
            }
            #pragma unroll
            for (int j = 0; j < 4; ++j) {
                const f16x8 bf = *(const f16x8*)(ws + (size_t)(240 + kc*16 + 4*w + j)*1024 + lane*16);
                #pragma unroll
                for (int rt = 0; rt < 4; ++rt)
                    acct[rt][j] = __builtin_amdgcn_mfma_f32_16x16x32_f16(a[rt], bf, acct[rt][j], 0, 0, 0);
            }
        }
        #pragma unroll
        for (int j = 0; j < 4; ++j) {
            const int col = (4*w + j)*16 + ln;
            const float tb = t_b[col], g2 = bn2g[col]*INVV, b2 = bn2b[col];
            float m = -3.4e38f;
            #pragma unroll
            for (int rt = 0; rt < 4; ++rt)
                #pragma unroll
                for (int r = 0; r < 4; ++r) {
                    const int row = rt*16 + g4 + r;
                    const float tv = acct[rt][j][r] + tb;
                    const float rl = fmaxf(tv*g2 + b2, 0.f);
                    const float xv = (float)(*(const f16*)(s_xs + row*512 + swzb(row, col*2)));
                    m = fmaxf(m, xv + rl);
                }
            m = fmaxf(m, __shfl_xor(m, 16));
            m = fmaxf(m, __shfl_xor(m, 32));
            if ((lane >> 4) == 0)
                out[((size_t)bb*256 + col)*1024 + s] = m;
        }
    }
}

extern "C" void kernel_launch(void* const* d_in, const int* in_sizes, int n_in,
                              void* d_out, int out_size, void* d_ws, size_t ws_size,
                              hipStream_t stream) {
    (void)in_sizes; (void)n_in; (void)out_size; (void)ws_size;
    unsigned char* ws = (unsigned char*)d_ws;
    prep_weights<<<(NTILES*64 + 255)/256, 256, 0, stream>>>(
        (const float*)d_in[4],   // mlp_w
        (const float*)d_in[8],   // qk_w
        (const float*)d_in[9],   // v_w
        (const float*)d_in[11],  // t_w
        ws);
    cloudcrop_mfma<<<2048, 256, 0, stream>>>(
        (const float*)d_in[0],   // seed_xyz
        (const float*)d_in[1],   // pointcloud
        (const float*)d_in[2],   // vp_rot
        (const float*)d_in[3],   // up_feature
        (const float*)d_in[5],   // mlp_b
        (const float*)d_in[6],   // bn1_g
        (const float*)d_in[7],   // bn1_b
        (const float*)d_in[10],  // v_b
        (const float*)d_in[12],  // t_b
        (const float*)d_in[13],  // bn2_g
        (const float*)d_in[14],  // bn2_b
        ws,
        (float*)d_out);
}

// Round 3
// 172.095 us; speedup vs baseline: 16.5442x; 1.8478x over previous
//
#include <hip/hip_runtime.h>

// CloudCrop fused MFMA kernel, round 3: 2 blocks/CU (LDS ~70KB), fused D1+D2
// via wave-local bounce transpose, in-place Y, wave-parallel softmax.
// B=2,S=1024,N=10000,C=128,NS=64,hidden=256.

typedef _Float16 f16;
typedef _Float16 f16x8 __attribute__((ext_vector_type(8)));
typedef _Float16 f16x4v __attribute__((ext_vector_type(4)));
typedef float f32x4 __attribute__((ext_vector_type(4)));

constexpr int Nn = 10000;
constexpr float RAD2 = 0.05f * 0.05f;
constexpr float HMINf = -0.02f, HMAXf = 0.02f;
constexpr float INVV = 0.99999500003749968747f; // 1/sqrt(1+1e-5)

// ws tile map (1KB fragment tiles: [64 lanes][8 f16]):
//   WA: tiles   0..79   mlp (K padded 131->160; k 0..127=feat, 128..130=xyz)
//   WQ: tiles  80..111  qk_w
//   WV: tiles 112..239  v_w
//   WT: tiles 240..367  t_w
#define NTILES 368

__device__ __forceinline__ int swzb(int row, int colbyte) {
    return colbyte ^ ((row & 7) << 4);
}

__global__ void prep_weights(const float* __restrict__ mlp_w,
                             const float* __restrict__ qk_w,
                             const float* __restrict__ v_w,
                             const float* __restrict__ t_w,
                             unsigned char* __restrict__ ws) {
    const int tid = blockIdx.x * 256 + threadIdx.x;
    if (tid >= NTILES * 64) return;
    const int tile = tid >> 6, lane = tid & 63;
    const int ln = lane & 15, kg = lane >> 4;
    f16x8 v;
    if (tile < 80) {
        const int kc = tile / 16, ct = tile % 16;
        const int n = ct * 16 + ln, kb = kc * 32 + kg * 8;
        #pragma unroll
        for (int i = 0; i < 8; ++i) {
            const int k = kb + i;
            float x = (k < 128) ? mlp_w[n * 131 + 3 + k]
                    : ((k < 131) ? mlp_w[n * 131 + (k - 128)] : 0.f);
            v[i] = (f16)x;
        }
    } else if (tile < 112) {
        const int t2 = tile - 80; const int kc = t2 >> 2, ct = t2 & 3;
        const int n = ct * 16 + ln, kb = kc * 32 + kg * 8;
        #pragma unroll
        for (int i = 0; i < 8; ++i) v[i] = (f16)qk_w[n * 256 + kb + i];
    } else if (tile < 240) {
        const int t2 = tile - 112; const int kc = t2 >> 4, ct = t2 & 15;
        const int n = ct * 16 + ln, kb = kc * 32 + kg * 8;
        #pragma unroll
        for (int i = 0; i < 8; ++i) v[i] = (f16)v_w[n * 256 + kb + i];
    } else {
        const int t2 = tile - 240; const int kc = t2 >> 4, ct = t2 & 15;
        const int n = ct * 16 + ln, kb = kc * 32 + kg * 8;
        #pragma unroll
        for (int i = 0; i < 8; ++i) v[i] = (f16)t_w[n * 256 + kb + i];
    }
    *(f16x8*)(ws + (size_t)tid * 16) = v;
}

__launch_bounds__(256, 2)
__global__ void cloudcrop_mfma(
    const float* __restrict__ seed,  // (B,S,3)
    const float* __restrict__ pc,    // (B,N,3)
    const float* __restrict__ rot,   // (B,S,3,3)
    const float* __restrict__ up,    // (B,C,N)
    const float* __restrict__ mlp_b,
    const float* __restrict__ bn1g,
    const float* __restrict__ bn1b,
    const float* __restrict__ v_b,
    const float* __restrict__ t_b,
    const float* __restrict__ bn2g,
    const float* __restrict__ bn2b,
    const unsigned char* __restrict__ ws,
    float* __restrict__ out)         // (B,256,S) f32
{
    // LDS (f16 arrays XOR-swizzled: byte ^= (row&7)<<4)
    __shared__ __align__(16) unsigned char s_x[64 * 512];   // X [64][256] s512B; Y overwrites in D-epi
    __shared__ __align__(16) unsigned char s_g[25600];      // G[64][192] s384B | {Q/attT [64][64] s128B @0, Sf32 [64][68] @8192}
    __shared__ __align__(16) unsigned char s_bounce[8192];  // per-wave 2KB V-transpose tile
    __shared__ int   cand_i[4][64];
    __shared__ float cand_x[4][64], cand_y[4][64], cand_z[4][64];
    __shared__ int   cand_n[4];
    __shared__ int   idx_s[64];
    __shared__ float colsum[64];

    const int grp = blockIdx.x;
    const int bb = grp >> 10;
    const int s  = grp & 1023;
    const int t  = threadIdx.x;
    const int lane = t & 63;
    const int w    = t >> 6;
    const int ln   = lane & 15;
    const int kg16 = (lane >> 4) * 16;
    const int g4   = (lane >> 4) * 4;

    unsigned char* G = s_g;  // [64][192] f16 during gather/A

    // ---------- Phase 0: selection scan, 4 waves x 2500 pts, no early exit --
    {
        const float sx = seed[grp*3+0], sy = seed[grp*3+1], sz = seed[grp*3+2];
        const float R0 = rot[grp*9+0], R1 = rot[grp*9+1], R2 = rot[grp*9+2];
        const float R3 = rot[grp*9+3], R4 = rot[grp*9+4], R5 = rot[grp*9+5];
        const float R6 = rot[grp*9+6], R7 = rot[grp*9+7], R8 = rot[grp*9+8];
        int count = 0;
        const int lo = w * 2500, hi = lo + 2500;
        for (int base = lo; base < hi; base += 64) {
            const int n = base + lane;
            bool m = false; float rx = 0.f, ry = 0.f, rz = 0.f;
            if (n < hi) {
                const float px = pc[(bb*Nn + n)*3+0] - sx;
                const float py = pc[(bb*Nn + n)*3+1] - sy;
                const float pz = pc[(bb*Nn + n)*3+2] - sz;
                rx = px*R0 + py*R3 + pz*R6;
                ry = px*R1 + py*R4 + pz*R7;
                rz = px*R2 + py*R5 + pz*R8;
                m = (ry*ry + rz*rz < RAD2) && (rx > HMINf) && (rx < HMAXf);
            }
            const unsigned long long bal = __ballot(m);
            const int below = __popcll(bal & ((1ull << lane) - 1ull));
            const int pos = count + below;
            if (m && pos < 64) {
                cand_i[w][pos] = n;
                cand_x[w][pos] = rx; cand_y[w][pos] = ry; cand_z[w][pos] = rz;
            }
            count += __popcll(bal);
        }
        if (lane == 0) cand_n[w] = count < 64 ? count : 64;
    }
    __syncthreads();

    // ---------- Merge (ordered) + xyz into G ------------------------------
    if (t < 64) {
        const int c0 = cand_n[0], c1 = cand_n[1], c2 = cand_n[2], c3 = cand_n[3];
        const int o1 = c0, o2 = c0 + c1, o3 = o2 + c2;
        int total = o3 + c3; if (total > 64) total = 64;
        int myi; float rx, ry, rz;
        if (total > 0) {
            const int pp = (t < total) ? t : 0;  // fill slots with global-first
            int sw_, sq;
            if      (pp >= o3) { sw_ = 3; sq = pp - o3; }
            else if (pp >= o2) { sw_ = 2; sq = pp - o2; }
            else if (pp >= o1) { sw_ = 1; sq = pp - o1; }
            else               { sw_ = 0; sq = pp; }
            myi = cand_i[sw_][sq];
            rx = cand_x[sw_][sq]; ry = cand_y[sw_][sq]; rz = cand_z[sw_][sq];
        } else {
            const float sx = seed[grp*3+0], sy = seed[grp*3+1], sz = seed[grp*3+2];
            const float px = pc[(bb*Nn)*3+0] - sx;
            const float py = pc[(bb*Nn)*3+1] - sy;
            const float pz = pc[(bb*Nn)*3+2] - sz;
            rx = px*rot[grp*9+0] + py*rot[grp*9+3] + pz*rot[grp*9+6];
            ry = px*rot[grp*9+1] + py*rot[grp*9+4] + pz*rot[grp*9+7];
            rz = px*rot[grp*9+2] + py*rot[grp*9+5] + pz*rot[grp*9+8];
            myi = 0;
        }
        idx_s[t] = myi;
        *(f16*)(G + t*384 + swzb(t, 256)) = (f16)rx;  // k=128
        *(f16*)(G + t*384 + swzb(t, 258)) = (f16)ry;  // k=129
        *(f16*)(G + t*384 + swzb(t, 260)) = (f16)rz;  // k=130
    }
    {   // zero pad k = 131..159
        const int row = t & 63;
        #pragma unroll
        for (int i = 0; i < 8; ++i) {
            const int c = 131 + w * 8 + i;
            if (c < 160) *(f16*)(G + row*384 + swzb(row, c*2)) = (f16)0.f;
        }
    }
    __syncthreads();

    // ---------- Phase 1: feature gather -> G (k=0..127) ---------------------
    {
        const int myn = idx_s[lane];
        const float* uprow = up + (size_t)bb * 128 * Nn;
        #pragma unroll
        for (int j8 = 0; j8 < 4; ++j8) {
            f16x8 v;
            #pragma unroll
            for (int i = 0; i < 8; ++i) {
                const int c = w * 32 + j8 * 8 + i;
                v[i] = (f16)uprow[(size_t)c * Nn + myn];
            }
            *(f16x8*)(G + lane*384 + swzb(lane, w*64 + j8*16)) = v;
        }
    }
    __syncthreads();

    // ---------- Phase A: H = G(64x160) @ WA -> X f16 (+bias,BN1,ReLU) -------
    {
        f32x4 acc[4][4] = {};
        #pragma unroll 2
        for (int kc = 0; kc < 5; ++kc) {
            f16x8 a[4];
            #pragma unroll
            for (int rt = 0; rt < 4; ++rt) {
                const int row = rt*16 + ln;
                a[rt] = *(const f16x8*)(G + row*384 + swzb(row, kc*64 + kg16));
            }
            #pragma unroll
            for (int j = 0; j < 4; ++j) {
                const f16x8 bf = *(const f16x8*)(ws + (size_t)(kc*16 + 4*w + j)*1024 + lane*16);
                #pragma unroll
                for (int rt = 0; rt < 4; ++rt)
                    acc[rt][j] = __builtin_amdgcn_mfma_f32_16x16x32_f16(a[rt], bf, acc[rt][j], 0, 0, 0);
            }
        }
        #pragma unroll
        for (int j = 0; j < 4; ++j) {
            const int col = (4*w + j)*16 + ln;
            const float mb = mlp_b[col], g1 = bn1g[col]*INVV, b1 = bn1b[col];
            #pragma unroll
            for (int rt = 0; rt < 4; ++rt)
                #pragma unroll
                for (int r = 0; r < 4; ++r) {
                    const int row = rt*16 + g4 + r;
                    const float h = fmaxf((acc[rt][j][r] + mb)*g1 + b1, 0.f);
                    *(f16*)(s_x + row*512 + swzb(row, col*2)) = (f16)h;
                }
        }
    }
    __syncthreads();

    // ---------- Phase B: Q = X @ WQ (64x64), wave w -> coltile w ------------
    {
        f32x4 accq[4] = {};
        #pragma unroll
        for (int kc = 0; kc < 8; ++kc) {
            const f16x8 bf = *(const f16x8*)(ws + (size_t)(80 + kc*4 + w)*1024 + lane*16);
            #pragma unroll
            for (int rt = 0; rt < 4; ++rt) {
                const int row = rt*16 + ln;
                const f16x8 a = *(const f16x8*)(s_x + row*512 + swzb(row, kc*64 + kg16));
                accq[rt] = __builtin_amdgcn_mfma_f32_16x16x32_f16(a, bf, accq[rt], 0, 0, 0);
            }
        }
        const int col = w*16 + ln;
        #pragma unroll
        for (int rt = 0; rt < 4; ++rt)
            #pragma unroll
            for (int r = 0; r < 4; ++r) {
                const int row = rt*16 + g4 + r;
                *(f16*)(s_g + row*128 + swzb(row, col*2)) = (f16)accq[rt][r];
            }
    }
    __syncthreads();

    // ---------- Phase C: S = Q @ Q^T (64x64) f32 ----------------------------
    {
        f32x4 accs[4] = {};
        #pragma unroll
        for (int kc = 0; kc < 2; ++kc) {
            const int rowb = w*16 + ln;
            const f16x8 bf = *(const f16x8*)(s_g + rowb*128 + swzb(rowb, kc*64 + kg16));
            #pragma unroll
            for (int rt = 0; rt < 4; ++rt) {
                const int row = rt*16 + ln;
                const f16x8 a = *(const f16x8*)(s_g + row*128 + swzb(row, kc*64 + kg16));
                accs[rt] = __builtin_amdgcn_mfma_f32_16x16x32_f16(a, bf, accs[rt], 0, 0, 0);
            }
        }
        float* Sf = (float*)(s_g + 8192);
        const int col = w*16 + ln;
        #pragma unroll
        for (int rt = 0; rt < 4; ++rt)
            #pragma unroll
            for (int r = 0; r < 4; ++r)
                Sf[(rt*16 + g4 + r)*68 + col] = accs[rt][r];
    }
    __syncthreads();

    // ---------- Softmax: 4 lanes per row, rows w*16+(lane>>2) ---------------
    {
        float* Sf = (float*)(s_g + 8192);
        const int r4 = lane >> 2, q4 = lane & 3;
        const int row = w*16 + r4;
        f32x4 vb4[4];
        #pragma unroll
        for (int c4 = 0; c4 < 4; ++c4)
            vb4[c4] = *(const f32x4*)(Sf + row*68 + q4*16 + c4*4);
        float mx = -3.4e38f;
        #pragma unroll
        for (int c4 = 0; c4 < 4; ++c4)
            #pragma unroll
            for (int e = 0; e < 4; ++e) mx = fmaxf(mx, vb4[c4][e]);
        mx = fmaxf(mx, __shfl_xor(mx, 1));
        mx = fmaxf(mx, __shfl_xor(mx, 2));
        float sm = 0.f;
        #pragma unroll
        for (int c4 = 0; c4 < 4; ++c4)
            #pragma unroll
            for (int e = 0; e < 4; ++e) {
                const float ev = __expf(vb4[c4][e] - mx);
                vb4[c4][e] = ev; sm += ev;
            }
        sm += __shfl_xor(sm, 1);
        sm += __shfl_xor(sm, 2);
        const float inv = 1.0f / sm;
        // attT[j = q4*16+c][i = row]
        #pragma unroll
        for (int c4 = 0; c4 < 4; ++c4)
            #pragma unroll
            for (int e = 0; e < 4; ++e) {
                const int j = q4*16 + c4*4 + e;
                *(f16*)(s_g + j*128 + swzb(j, row*2)) = (f16)(vb4[c4][e] * inv);
            }
    }
    __syncthreads();

    // ---------- colsum[j] = 1e-9 + sum_i att[i][j] (row-sum of attT) --------
    if (t < 64) {
        float ssum = 0.f;
        #pragma unroll
        for (int c8 = 0; c8 < 8; ++c8) {
            const f16x8 vv = *(const f16x8*)(s_g + t*128 + swzb(t, c8*16));
            #pragma unroll
            for (int i = 0; i < 8; ++i) ssum += (float)vv[i];
        }
        colsum[t] = 1e-9f + ssum;
    }
    __syncthreads();

    // ---------- Phase D: V=X@WV+vb, wave-local transpose, XR=attT@V ---------
    f32x4 accr[4][4] = {};
    {
        // attT A-fragments (k = sample i), hoisted
        f16x8 a2[2][4];
        #pragma unroll
        for (int kc = 0; kc < 2; ++kc)
            #pragma unroll
            for (int rt = 0; rt < 4; ++rt) {
                const int row = rt*16 + ln;
                a2[kc][rt] = *(const f16x8*)(s_g + row*128 + swzb(row, kc*64 + kg16));
            }
        // V accumulate (pre-bias)
        f32x4 accv[4][4] = {};
        #pragma unroll 2
        for (int kc = 0; kc < 8; ++kc) {
            f16x8 a[4];
            #pragma unroll
            for (int rt = 0; rt < 4; ++rt) {
                const int row = rt*16 + ln;
                a[rt] = *(const f16x8*)(s_x + row*512 + swzb(row, kc*64 + kg16));
            }
            #pragma unroll
            for (int j = 0; j < 4; ++j) {
                const f16x8 bf = *(const f16x8*)(ws + (size_t)(112 + kc*16 + 4*w + j)*1024 + lane*16);
                #pragma unroll
                for (int rt = 0; rt < 4; ++rt)
                    accv[rt][j] = __builtin_amdgcn_mfma_f32_16x16x32_f16(a[rt], bf, accv[rt][j], 0, 0, 0);
            }
        }
        // per-j: bounce-transpose V tile (wave-local), then XR MFMA
        unsigned char* bw = s_bounce + w*2048;  // [16 ch][64 samples] f16
        #pragma unroll
        for (int j = 0; j < 4; ++j) {
            const float vb = v_b[(4*w + j)*16 + ln];
            #pragma unroll
            for (int rt = 0; rt < 4; ++rt)
                #pragma unroll
                for (int r = 0; r < 4; ++r) {
                    const int sr = rt*16 + g4 + r;  // sample index
                    *(f16*)(bw + ln*128 + ((sr*2) ^ ((ln & 7) << 4))) = (f16)(accv[rt][j][r] + vb);
                }
            asm volatile("s_waitcnt lgkmcnt(0)" ::: "memory");
            #pragma unroll
            for (int kc = 0; kc < 2; ++kc) {
                const f16x8 bf = *(const f16x8*)(bw + ln*128 + ((kc*64 + kg16) ^ ((ln & 7) << 4)));
                #pragma unroll
                for (int rt = 0; rt < 4; ++rt)
                    accr[rt][j] = __builtin_amdgcn_mfma_f32_16x16x32_f16(a2[kc][rt], bf, accr[rt][j], 0, 0, 0);
            }
            asm volatile("" ::: "memory");
        }
    }
    __syncthreads();  // all waves' X A-frag reads done before Y overwrite

    // ---------- D-epilogue: Y = X - XR/colsum (in-place), keep X in regs ----
    f16x4v xsave[4][4];
    #pragma unroll
    for (int j = 0; j < 4; ++j) {
        const int col = (4*w + j)*16 + ln;
        #pragma unroll
        for (int rt = 0; rt < 4; ++rt) {
            f16x4v xs4;
            #pragma unroll
            for (int r = 0; r < 4; ++r) {
                const int row = rt*16 + g4 + r;
                const f16 xv = *(const f16*)(s_x + row*512 + swzb(row, col*2));
                xs4[r] = xv;
                const float yv = (float)xv - accr[rt][j][r] / colsum[row];
                *(f16*)(s_x + row*512 + swzb(row, col*2)) = (f16)yv;
            }
            xsave[j][rt] = xs4;
        }
    }
    __syncthreads();

    // ---------- Phase E: T = Y @ WT + t_b; out = maxpool(X + relu(BN2)) -----
    {
        f32x4 acct[4][4] = {};
        #pragma unroll 2
        for (int kc = 0; kc < 8; ++kc) {
            f16x8 a[4];
            #pragma unroll
            for (int rt = 0; rt < 4; ++rt) {
                const int row = rt*16 + ln;
                a[rt] = *(const f16x8*)(s_x + row*512 + swzb(row, kc*64 + kg16));  // Y
            }
            #pragma unroll
            for (int j = 0; j < 4; ++j) {
                const f16x8 bf = *(const f16x8*)(ws + (size_t)(240 + kc*16 + 4*w + j)*1024 + lane*16);
                #pragma unroll
                for (int rt = 0; rt < 4; ++rt)
                    acct[rt][j] = __builtin_amdgcn_mfma_f32_16x16x32_f16(a[rt], bf, acct[rt][j], 0, 0, 0);
            }
        }
        #pragma unroll
        for (int j = 0; j < 4; ++j) {
            const int col = (4*w + j)*16 + ln;
            const float tb = t_b[col], g2 = bn2g[col]*INVV, b2 = bn2b[col];
            float m = -3.4e38f;
            #pragma unroll
            for (int rt = 0; rt < 4; ++rt)
                #pragma unroll
                for (int r = 0; r < 4; ++r) {
                    const float tv = acct[rt][j][r] + tb;
                    const float rl = fmaxf(tv*g2 + b2, 0.f);
                    const float xv = (float)xsave[j][rt][r];
                    m = fmaxf(m, xv + rl);
                }
            m = fmaxf(m, __shfl_xor(m, 16));
            m = fmaxf(m, __shfl_xor(m, 32));
            if ((lane >> 4) == 0)
                out[((size_t)bb*256 + col)*1024 + s] = m;
        }
    }
}

extern "C" void kernel_launch(void* const* d_in, const int* in_sizes, int n_in,
                              void* d_out, int out_size, void* d_ws, size_t ws_size,
                              hipStream_t stream) {
    (void)in_sizes; (void)n_in; (void)out_size; (void)ws_size;
    unsigned char* ws = (unsigned char*)d_ws;
    prep_weights<<<(NTILES*64 + 255)/256, 256, 0, stream>>>(
        (const float*)d_in[4],   // mlp_w
        (const float*)d_in[8],   // qk_w
        (const float*)d_in[9],   // v_w
        (const float*)d_in[11],  // t_w
        ws);
    cloudcrop_mfma<<<2048, 256, 0, stream>>>(
        (const float*)d_in[0],   // seed_xyz
        (const float*)d_in[1],   // pointcloud
        (const float*)d_in[2],   // vp_rot
        (const float*)d_in[3],   // up_feature
        (const float*)d_in[5],   // mlp_b
        (const float*)d_in[6],   // bn1_g
        (const float*)d_in[7],   // bn1_b
        (const float*)d_in[10],  // v_b
        (const float*)d_in[12],  // t_b
        (const float*)d_in[13],  // bn2_g
        (const float*)d_in[14],  // bn2_b
        ws,
        (float*)d_out);
}